// Round 1
// baseline (123.901 us; speedup 1.0000x reference)
//
#include <hip/hip_runtime.h>
#include <math.h>

#define NB 8
#define NT 4096
#define ND 1024
#define NL 3
#define NO 4
#define NLO 12
#define TWO_PI_D 6.283185307179586476925286766559
#define DT_D 0.1
#define NSTEPS 10
#define THRESH_D 0.3

#define A_ROWS 64
#define A_KC 128

// ---------------- Kernel A: proj (f64 dots) + initial phases ----------------
// block 256 threads = 4 waves; 64 rows/block; K-chunks of 128 floats.
// LDS: x tile [64][132] f32 (padded vs bank conflicts) + W chunk as f64.
__global__ __launch_bounds__(256) void k_proj_phase(
    const float* __restrict__ x, const float* __restrict__ W,
    double* __restrict__ ws_ph)
{
    __shared__ float xl[A_ROWS][A_KC + 4];
    __shared__ double wl[NLO][A_KC];
    const int tid = threadIdx.x;
    const int row = tid & 63;
    const int seg = tid >> 6;              // 4 segments of 32 d each
    const long row0 = (long)blockIdx.x * A_ROWS;

    double acc[NLO];
#pragma unroll
    for (int k = 0; k < NLO; ++k) acc[k] = 0.0;

    for (int c = 0; c < ND / A_KC; ++c) {
        // stage x tile (coalesced float4)
#pragma unroll
        for (int p = 0; p < 8; ++p) {
            int f4 = tid + p * 256;        // 0..2047
            int r = f4 >> 5;               // /32 f4 per row
            int col = f4 & 31;
            float4 v = *reinterpret_cast<const float4*>(
                x + (row0 + r) * ND + (long)c * A_KC + col * 4);
            *reinterpret_cast<float4*>(&xl[r][col * 4]) = v;
        }
        // stage W chunk, converted to f64 once (avoids per-FMA converts)
#pragma unroll
        for (int p = 0; p < 6; ++p) {
            int idx = tid + p * 256;       // 0..1535
            int lo = idx >> 7;
            int dd = idx & 127;
            wl[lo][dd] = (double)W[(long)lo * ND + c * A_KC + dd];
        }
        __syncthreads();
        const int d0 = seg * 32;
#pragma unroll 2
        for (int dd = 0; dd < 32; dd += 4) {
            float4 xv = *reinterpret_cast<const float4*>(&xl[row][d0 + dd]);
            double x0 = (double)xv.x, x1 = (double)xv.y;
            double x2 = (double)xv.z, x3 = (double)xv.w;
#pragma unroll
            for (int lo = 0; lo < NLO; ++lo) {
                double a = acc[lo];
                a = fma(x0, wl[lo][d0 + dd + 0], a);
                a = fma(x1, wl[lo][d0 + dd + 1], a);
                a = fma(x2, wl[lo][d0 + dd + 2], a);
                a = fma(x3, wl[lo][d0 + dd + 3], a);
                acc[lo] = a;
            }
        }
        __syncthreads();
    }
    // cross-segment reduction through LDS (reuse x tile area: 24576B <= 33792B)
    double* red = reinterpret_cast<double*>(&xl[0][0]);
#pragma unroll
    for (int k = 0; k < NLO; ++k) red[k * 256 + tid] = acc[k];
    __syncthreads();
    if (tid < 64) {
        double proj[NLO];
#pragma unroll
        for (int k = 0; k < NLO; ++k)
            proj[k] = (red[k * 256 + row] + red[k * 256 + 64 + row]) +
                      (red[k * 256 + 128 + row] + red[k * 256 + 192 + row]);
        const long r = row0 + row;
        const int b = (int)(r >> 12);          // / NT
        const int t = (int)(r & (NT - 1));
#pragma unroll
        for (int l = 0; l < NL; ++l) {
#pragma unroll
            for (int o = 0; o < NO; ++o) {
                double y = proj[l * NO + o];
                double xx = proj[l * NO + ((o + 3) & 3)] + 1e-8;
                double ph = atan2(y, xx);
                if (ph < 0.0) ph += TWO_PI_D;  // matches np.mod semantics here
                ws_ph[((long)((l * NB + b) * NO + o)) * NT + t] = ph;
            }
        }
    }
}

// ---------------- Kernel B: 10 Kuramoto steps, one block per (l,b,o) --------
#define B_THREADS 512
#define B_ELEMS (NT / B_THREADS)   // 8

__global__ __launch_bounds__(B_THREADS) void k_kuramoto(
    const float* __restrict__ omegas, const float* __restrict__ Ks,
    double* __restrict__ ws_ph, double* __restrict__ ws_r,
    float* __restrict__ out_ph)
{
    const int g = blockIdx.x;              // (l*NB + b)*NO + o
    const int l = g >> 5;
    const int b = (g >> 2) & 7;
    const int o = g & 3;
    const double om = (double)omegas[l * NO + o];
    const double Kv = (double)Ks[l];
    const int tid = threadIdx.x;
    const int wid = tid >> 6;
    const int lane = tid & 63;
    __shared__ double lds[18];

    double ph[B_ELEMS];
#pragma unroll
    for (int k = 0; k < B_ELEMS; ++k)
        ph[k] = ws_ph[(long)g * NT + tid + k * B_THREADS];

    double s[B_ELEMS], c[B_ELEMS];
    for (int step = 0; step <= NSTEPS; ++step) {
        double ts = 0.0, tc = 0.0;
#pragma unroll
        for (int k = 0; k < B_ELEMS; ++k) {
            sincos(ph[k], &s[k], &c[k]);
            ts += s[k]; tc += c[k];
        }
#pragma unroll
        for (int off = 32; off > 0; off >>= 1) {
            ts += __shfl_down(ts, off);
            tc += __shfl_down(tc, off);
        }
        if (lane == 0) { lds[wid] = ts; lds[8 + wid] = tc; }
        __syncthreads();
        if (step == NSTEPS) break;   // final sincos + partials done; no update
        if (tid == 0) {
            double S = 0.0, C = 0.0;
#pragma unroll
            for (int w = 0; w < 8; ++w) { S += lds[w]; C += lds[8 + w]; }
            double mean = atan2(S / (double)NT, C / (double)NT);
            double sm, cm; sincos(mean, &sm, &cm);
            lds[16] = sm; lds[17] = cm;
        }
        __syncthreads();
        const double sm = lds[16], cm = lds[17];
#pragma unroll
        for (int k = 0; k < B_ELEMS; ++k) {
            // sin(mean - ph) = sin(mean)cos(ph) - cos(mean)sin(ph)
            double sv = sm * c[k] - cm * s[k];
            double coupling = Kv * sv / (double)NT;
            double val = ph[k] + DT_D * (om + coupling);
            // val in [0, 2pi + 0.45): conditional subtract == fmod exactly (Sterbenz)
            if (val >= TWO_PI_D) val -= TWO_PI_D;
            if (val < 0.0) val += TWO_PI_D;
            ph[k] = val;
        }
        __syncthreads();               // protect lds before next step's writes
    }
    if (tid == 0) {
        double S = 0.0, C = 0.0;
#pragma unroll
        for (int w = 0; w < 8; ++w) { S += lds[w]; C += lds[8 + w]; }
        double Sm = S / (double)NT, Cm = C / (double)NT;
        ws_r[g] = sqrt(Sm * Sm + Cm * Cm);
    }
#pragma unroll
    for (int k = 0; k < B_ELEMS; ++k) {
        int t = tid + k * B_THREADS;
        ws_ph[(long)g * NT + t] = ph[k];                                // final f64 phases for k_mask
        out_ph[((long)(l * NB + b) * NT + t) * NO + o] = (float)ph[k];  // (L,B,T,O) output
    }
}

// ---------------- Kernel C: windowed coherence -> boundary mask -------------
__global__ __launch_bounds__(256) void k_mask(
    const double* __restrict__ ws_ph, float* __restrict__ out_mask)
{
    const int bid = blockIdx.x;            // 24 lb * 16 t-slices
    const int lb = bid >> 4;               // l*NB + b
    const int t0 = ((bid & 15) << 8) + threadIdx.x;  // 0..4095
    float* mrow = out_mask + (long)lb * (NT - 2);
    if ((bid & 15) == 0 && threadIdx.x < 2) mrow[threadIdx.x] = 0.0f;  // pad zeros
    if (t0 >= NT - 4) return;
    double q[3] = {0.0, 0.0, 0.0};
#pragma unroll
    for (int o = 0; o < NO; ++o) {
        const double* p = ws_ph + ((long)lb * NO + o) * NT + t0;
        double sv[5], cv[5];
#pragma unroll
        for (int j = 0; j < 5; ++j) sincos(p[j], &sv[j], &cv[j]);
#pragma unroll
        for (int j = 0; j < 3; ++j) {
            double ms = ((sv[j] + sv[j + 1]) + sv[j + 2]) / 3.0;
            double mc = ((cv[j] + cv[j + 1]) + cv[j + 2]) / 3.0;
            q[j] += sqrt(ms * ms + mc * mc);
        }
    }
    double coh0 = q[0] / 4.0, coh1 = q[1] / 4.0, coh2 = q[2] / 4.0;
    bool cond = (coh1 < coh0 - THRESH_D) && (coh1 < coh2 - THRESH_D);
    mrow[2 + t0] = cond ? 1.0f : 0.0f;
}

// ---------------- Kernel D: level coherences (24 values) --------------------
__global__ void k_level(const double* __restrict__ ws_r, float* __restrict__ out_lvl)
{
    const int tid = threadIdx.x;
    if (tid < NB * NL) {
        const int b = tid / NL, l = tid % NL;   // output is (B, L)
        const double* r = ws_r + (long)(l * NB + b) * NO;
        double m = (((r[0] + r[1]) + r[2]) + r[3]) / 4.0;
        out_lvl[tid] = (float)m;
    }
}

extern "C" void kernel_launch(void* const* d_in, const int* in_sizes, int n_in,
                              void* d_out, int out_size, void* d_ws, size_t ws_size,
                              hipStream_t stream)
{
    const float* x      = (const float*)d_in[0];
    const float* W      = (const float*)d_in[1];
    const float* omegas = (const float*)d_in[2];
    const float* Ks     = (const float*)d_in[3];
    float* out = (float*)d_out;

    double* ws_ph = (double*)d_ws;                          // 393216 f64 (3.15 MB)
    double* ws_r  = ws_ph + (long)NL * NB * NT * NO;        // 96 f64

    float* out_ph   = out;            // 393216
    float* out_lvl  = out + 393216;   // 24
    float* out_mask = out + 393240;   // 98256

    k_proj_phase<<<NB * NT / A_ROWS, 256, 0, stream>>>(x, W, ws_ph);
    k_kuramoto<<<NL * NB * NO, B_THREADS, 0, stream>>>(omegas, Ks, ws_ph, ws_r, out_ph);
    k_mask<<<24 * 16, 256, 0, stream>>>(ws_ph, out_mask);
    k_level<<<1, 64, 0, stream>>>(ws_r, out_lvl);
}

// Round 2
// 79.747 us; speedup vs baseline: 1.5537x; 1.5537x over previous
//
#include <hip/hip_runtime.h>
#include <math.h>

#define NB 8
#define NT 4096
#define ND 1024
#define NL 3
#define NO 4
#define NLO 12
#define TWO_PI_D 6.283185307179586476925286766559
#define DT_D 0.1
#define NSTEPS 10
#define THRESH_D 0.3

#define XPAD 132              // x tile row stride in f32 (mult of 4 for float4 align)

// ------------- Kernel W-prep: W f32 -> f64 (96 KB, L2-resident) -------------
__global__ __launch_bounds__(256) void k_wprep(const float* __restrict__ W,
                                               double* __restrict__ wsW)
{
    int i = blockIdx.x * 256 + threadIdx.x;
    if (i < NLO * ND) wsW[i] = (double)W[i];
}

// ------------- Kernel A: proj (f64 dots) + initial phase/sin/cos ------------
// 256 thr = 4 waves; 64 rows/block; thread = (rowslot 0..15, seg 0..15);
// thread owns 4 rows x (8 d per 128-d chunk); W read as b128 f64x2 (16-lane
// broadcast groups, <=2-way bank conflict); acc 4x12 f64 in VGPRs.
__global__ __launch_bounds__(256, 2) void k_proj(
    const float* __restrict__ x, const double* __restrict__ wsW,
    double* __restrict__ ws_ph, double* __restrict__ ws_s,
    double* __restrict__ ws_c)
{
    __shared__ float  xl[64 * XPAD];          // 33792 B
    __shared__ double wl[NLO * 128];          // 12288 B
    __shared__ double red[4 * 16 * 4 * 13];   // 26624 B  (pad 13 vs bank clash)

    const int tid = threadIdx.x;
    const int rowslot = tid & 15;
    const int seg = tid >> 4;
    const long row0 = (long)blockIdx.x * 64;

    double acc[4][NLO];
#pragma unroll
    for (int j = 0; j < 4; ++j)
#pragma unroll
        for (int lo = 0; lo < NLO; ++lo) acc[j][lo] = 0.0;

    for (int c = 0; c < ND / 128; ++c) {
        // stage x tile: 2048 float4, coalesced
#pragma unroll
        for (int p = 0; p < 8; ++p) {
            int id = p * 256 + tid;
            int r = id >> 5, col = id & 31;
            float4 v = *reinterpret_cast<const float4*>(
                x + (row0 + r) * ND + c * 128 + col * 4);
            *reinterpret_cast<float4*>(&xl[r * XPAD + col * 4]) = v;
        }
        // stage W chunk as f64: 768 double2, coalesced
#pragma unroll
        for (int p = 0; p < 3; ++p) {
            int id = p * 256 + tid;
            int lo = id >> 6, dc = id & 63;
            double2 v = *reinterpret_cast<const double2*>(
                wsW + lo * ND + c * 128 + dc * 2);
            *reinterpret_cast<double2*>(&wl[lo * 128 + dc * 2]) = v;
        }
        __syncthreads();

        const int d0 = seg * 8;
        float xs[4][8];
#pragma unroll
        for (int j = 0; j < 4; ++j) {
            const float* xr = &xl[(rowslot * 4 + j) * XPAD + d0];
            float4 a = *reinterpret_cast<const float4*>(xr);
            float4 b = *reinterpret_cast<const float4*>(xr + 4);
            xs[j][0] = a.x; xs[j][1] = a.y; xs[j][2] = a.z; xs[j][3] = a.w;
            xs[j][4] = b.x; xs[j][5] = b.y; xs[j][6] = b.z; xs[j][7] = b.w;
        }
#pragma unroll
        for (int dp = 0; dp < 4; ++dp) {
            double2 wv[NLO];
#pragma unroll
            for (int lo = 0; lo < NLO; ++lo)
                wv[lo] = *reinterpret_cast<const double2*>(
                    &wl[lo * 128 + d0 + dp * 2]);
#pragma unroll
            for (int j = 0; j < 4; ++j) {
                double x0 = (double)xs[j][2 * dp];
                double x1 = (double)xs[j][2 * dp + 1];
#pragma unroll
                for (int lo = 0; lo < NLO; ++lo)
                    acc[j][lo] = fma(x1, wv[lo].y, fma(x0, wv[lo].x, acc[j][lo]));
            }
        }
        __syncthreads();
    }

    // fold the 4 segs living in this wave (lanes xor 16, 32)
#pragma unroll
    for (int j = 0; j < 4; ++j)
#pragma unroll
        for (int lo = 0; lo < NLO; ++lo) {
            double v = acc[j][lo];
            v += __shfl_xor(v, 16, 64);
            v += __shfl_xor(v, 32, 64);
            acc[j][lo] = v;
        }
    const int wv_ = tid >> 6;
    if ((tid & 63) < 16) {
#pragma unroll
        for (int j = 0; j < 4; ++j)
#pragma unroll
            for (int lo = 0; lo < NLO; ++lo)
                red[((wv_ * 16 + rowslot) * 4 + j) * 13 + lo] = acc[j][lo];
    }
    __syncthreads();

    if (tid < 64) {
        const int rs = tid >> 2, j = tid & 3;
        double proj[NLO];
#pragma unroll
        for (int lo = 0; lo < NLO; ++lo)
            proj[lo] = (red[((rs) * 4 + j) * 13 + lo] +
                        red[((16 + rs) * 4 + j) * 13 + lo]) +
                       (red[((32 + rs) * 4 + j) * 13 + lo] +
                        red[((48 + rs) * 4 + j) * 13 + lo]);
        const long row = row0 + tid;
        const int b = (int)(row >> 12);
        const int t = (int)(row & (NT - 1));
#pragma unroll
        for (int l = 0; l < NL; ++l)
#pragma unroll
            for (int o = 0; o < NO; ++o) {
                double y = proj[l * NO + o];
                double xx = proj[l * NO + ((o + 3) & 3)] + 1e-8;
                double ph = atan2(y, xx);
                if (ph < 0.0) ph += TWO_PI_D;
                double r2 = sqrt(y * y + xx * xx);
                double s, cc;
                if (r2 > 0.0) { s = y / r2; cc = xx / r2; } else { s = 0.0; cc = 1.0; }
                long idx = ((long)((l * NB + b) * NO + o)) * NT + t;
                ws_ph[idx] = ph; ws_s[idx] = s; ws_c[idx] = cc;
            }
    }
}

// ------------- Kernel B: 10 Kuramoto steps via small-angle rotation ---------
#define B_THREADS 512
#define B_ELEMS (NT / B_THREADS)   // 8

__global__ __launch_bounds__(B_THREADS) void k_kuramoto(
    const float* __restrict__ omegas, const float* __restrict__ Ks,
    double* __restrict__ ws_ph, double* __restrict__ ws_s,
    double* __restrict__ ws_c, double* __restrict__ ws_r,
    float* __restrict__ out_ph)
{
    const int g = blockIdx.x;              // (l*NB + b)*NO + o
    const int l = g >> 5;
    const int b = (g >> 2) & 7;
    const int o = g & 3;
    const double om = (double)omegas[l * NO + o];
    const double Kv = (double)Ks[l];
    const int tid = threadIdx.x;
    const int wid = tid >> 6;
    const int lane = tid & 63;
    __shared__ double lds[18];

    double ph[B_ELEMS], s[B_ELEMS], c[B_ELEMS];
#pragma unroll
    for (int k = 0; k < B_ELEMS; ++k) {
        long idx = (long)g * NT + tid + k * B_THREADS;
        ph[k] = ws_ph[idx]; s[k] = ws_s[idx]; c[k] = ws_c[idx];
    }

    for (int step = 0; step < NSTEPS; ++step) {
        double ts = 0.0, tc = 0.0;
#pragma unroll
        for (int k = 0; k < B_ELEMS; ++k) { ts += s[k]; tc += c[k]; }
#pragma unroll
        for (int off = 32; off > 0; off >>= 1) {
            ts += __shfl_down(ts, off);
            tc += __shfl_down(tc, off);
        }
        if (lane == 0) { lds[wid] = ts; lds[8 + wid] = tc; }
        __syncthreads();
        if (tid == 0) {
            double S = 0.0, C = 0.0;
#pragma unroll
            for (int w = 0; w < 8; ++w) { S += lds[w]; C += lds[8 + w]; }
            double mean = atan2(S / (double)NT, C / (double)NT);
            double sm, cm; sincos(mean, &sm, &cm);
            lds[16] = sm; lds[17] = cm;
        }
        __syncthreads();
        const double sm = lds[16], cm = lds[17];
#pragma unroll
        for (int k = 0; k < B_ELEMS; ++k) {
            double sv = sm * c[k] - cm * s[k];
            double d = DT_D * (om + Kv * sv / (double)NT);
            double val = ph[k] + d;
            if (val >= TWO_PI_D) val -= TWO_PI_D;
            if (val < 0.0) val += TWO_PI_D;
            ph[k] = val;
            // rotate (s,c) by d: Taylor sincos, |d| <= ~0.45, err ~1e-10
            double z = d * d;
            double sd = d * fma(z, fma(z, fma(z, fma(z, 1.0 / 362880.0,
                          -1.0 / 5040.0), 1.0 / 120.0), -1.0 / 6.0), 1.0);
            double cd = fma(z, fma(z, fma(z, fma(z, 1.0 / 40320.0,
                          -1.0 / 720.0), 1.0 / 24.0), -0.5), 1.0);
            double sn = fma(s[k], cd, c[k] * sd);
            double cn = fma(c[k], cd, -(s[k] * sd));
            s[k] = sn; c[k] = cn;
        }
        __syncthreads();               // protect lds before next step's writes
    }
    // level coherence from final s,c
    {
        double ts = 0.0, tc = 0.0;
#pragma unroll
        for (int k = 0; k < B_ELEMS; ++k) { ts += s[k]; tc += c[k]; }
#pragma unroll
        for (int off = 32; off > 0; off >>= 1) {
            ts += __shfl_down(ts, off);
            tc += __shfl_down(tc, off);
        }
        if (lane == 0) { lds[wid] = ts; lds[8 + wid] = tc; }
        __syncthreads();
        if (tid == 0) {
            double S = 0.0, C = 0.0;
#pragma unroll
            for (int w = 0; w < 8; ++w) { S += lds[w]; C += lds[8 + w]; }
            double Sm = S / (double)NT, Cm = C / (double)NT;
            ws_r[g] = sqrt(Sm * Sm + Cm * Cm);
        }
    }
#pragma unroll
    for (int k = 0; k < B_ELEMS; ++k) {
        int t = tid + k * B_THREADS;
        long idx = (long)g * NT + t;
        ws_s[idx] = s[k]; ws_c[idx] = c[k];                             // final s,c for k_mask
        out_ph[((long)(l * NB + b) * NT + t) * NO + o] = (float)ph[k];  // (L,B,T,O)
    }
}

// ------------- Kernel C: windowed coherence -> boundary mask (no sincos) ----
__global__ __launch_bounds__(256) void k_mask(
    const double* __restrict__ ws_s, const double* __restrict__ ws_c,
    float* __restrict__ out_mask)
{
    const int bid = blockIdx.x;            // 24 lb * 16 t-slices
    const int lb = bid >> 4;               // l*NB + b
    const int t0 = ((bid & 15) << 8) + threadIdx.x;
    float* mrow = out_mask + (long)lb * (NT - 2);
    if ((bid & 15) == 0 && threadIdx.x < 2) mrow[threadIdx.x] = 0.0f;
    if (t0 >= NT - 4) return;
    double q[3] = {0.0, 0.0, 0.0};
#pragma unroll
    for (int o = 0; o < NO; ++o) {
        const double* ps = ws_s + ((long)lb * NO + o) * NT + t0;
        const double* pc = ws_c + ((long)lb * NO + o) * NT + t0;
        double sv[5], cv[5];
#pragma unroll
        for (int j = 0; j < 5; ++j) { sv[j] = ps[j]; cv[j] = pc[j]; }
#pragma unroll
        for (int j = 0; j < 3; ++j) {
            double ms = ((sv[j] + sv[j + 1]) + sv[j + 2]) / 3.0;
            double mc = ((cv[j] + cv[j + 1]) + cv[j + 2]) / 3.0;
            q[j] += sqrt(ms * ms + mc * mc);
        }
    }
    double coh0 = q[0] / 4.0, coh1 = q[1] / 4.0, coh2 = q[2] / 4.0;
    bool cond = (coh1 < coh0 - THRESH_D) && (coh1 < coh2 - THRESH_D);
    mrow[2 + t0] = cond ? 1.0f : 0.0f;
}

// ------------- Kernel D: level coherences (24 values) -----------------------
__global__ void k_level(const double* __restrict__ ws_r, float* __restrict__ out_lvl)
{
    const int tid = threadIdx.x;
    if (tid < NB * NL) {
        const int b = tid / NL, l = tid % NL;   // output is (B, L)
        const double* r = ws_r + (long)(l * NB + b) * NO;
        double m = (((r[0] + r[1]) + r[2]) + r[3]) / 4.0;
        out_lvl[tid] = (float)m;
    }
}

extern "C" void kernel_launch(void* const* d_in, const int* in_sizes, int n_in,
                              void* d_out, int out_size, void* d_ws, size_t ws_size,
                              hipStream_t stream)
{
    const float* x      = (const float*)d_in[0];
    const float* W      = (const float*)d_in[1];
    const float* omegas = (const float*)d_in[2];
    const float* Ks     = (const float*)d_in[3];
    float* out = (float*)d_out;

    double* wsW   = (double*)d_ws;                 // 12288 f64
    double* ws_ph = wsW + NLO * ND;                // 393216 f64
    double* ws_s  = ws_ph + (long)NLO * NB * NT;   // 393216 f64
    double* ws_c  = ws_s + (long)NLO * NB * NT;    // 393216 f64
    double* ws_r  = ws_c + (long)NLO * NB * NT;    // 96 f64

    float* out_ph   = out;            // 393216
    float* out_lvl  = out + 393216;   // 24
    float* out_mask = out + 393240;   // 98256

    k_wprep<<<(NLO * ND + 255) / 256, 256, 0, stream>>>(W, wsW);
    k_proj<<<NB * NT / 64, 256, 0, stream>>>(x, wsW, ws_ph, ws_s, ws_c);
    k_kuramoto<<<NL * NB * NO, B_THREADS, 0, stream>>>(omegas, Ks, ws_ph, ws_s, ws_c, ws_r, out_ph);
    k_mask<<<24 * 16, 256, 0, stream>>>(ws_s, ws_c, out_mask);
    k_level<<<1, 64, 0, stream>>>(ws_r, out_lvl);
}